// Round 1
// baseline (855.873 us; speedup 1.0000x reference)
//
#include <hip/hip_runtime.h>
#include <hip/hip_bf16.h>
#include <math.h>

#define N_NODES 20000
#define N_EDGES 320000
#define IN_F 256
#define OUT_F 64
#define HEADS 4
#define NCOL 256            // HEADS*OUT_F
#define LRELU_ALPHA 0.1f

// ---------------------------------------------------------------------------
// Kernel 1: C[M,256] = A[M,256] @ Weff[256,256]
// Weff[k][c] with c=h*64+j lives at W + h*IN_F*OUT_F + k*OUT_F + j
// BM=64, BN=256 (full width), BK=32. 8x8 register tile per thread.
// blockIdx.y selects (input1,Ws)->s_all vs (input2,Wt)->t_all.
// ---------------------------------------------------------------------------
__global__ __launch_bounds__(256) void gemm_kernel(
    const float* __restrict__ A0, const float* __restrict__ W0,
    const float* __restrict__ A1, const float* __restrict__ W1,
    float* __restrict__ C0, float* __restrict__ C1, int M)
{
    const float* A = (blockIdx.y == 0) ? A0 : A1;
    const float* W = (blockIdx.y == 0) ? W0 : W1;
    float* C       = (blockIdx.y == 0) ? C0 : C1;

    __shared__ float AsT[32][65];   // [k][row]; stride 65 -> conflict-free transposed stores
    __shared__ float Bs[32][NCOL];  // [k][c]

    const int tid = threadIdx.x;
    const int r0  = blockIdx.x * 64;
    const int tr  = tid >> 5;   // 0..7  -> rows tr*8..tr*8+7
    const int tc  = tid & 31;   // 0..31 -> cols tc*8..tc*8+7

    float acc[8][8];
#pragma unroll
    for (int i = 0; i < 8; ++i)
#pragma unroll
        for (int j = 0; j < 8; ++j) acc[i][j] = 0.f;

    for (int k0 = 0; k0 < IN_F; k0 += 32) {
        // ---- stage A tile (64 rows x 32 k), transposed into LDS ----
#pragma unroll
        for (int p = 0; p < 2; ++p) {
            int f4  = p * 256 + tid;     // 0..511 float4s
            int row = f4 >> 3;           // 0..63
            int kq  = f4 & 7;            // float4 index within 32-wide k strip
            float4 v = make_float4(0.f, 0.f, 0.f, 0.f);
            if (r0 + row < M)
                v = *(const float4*)(A + (size_t)(r0 + row) * IN_F + k0 + kq * 4);
            AsT[kq * 4 + 0][row] = v.x;
            AsT[kq * 4 + 1][row] = v.y;
            AsT[kq * 4 + 2][row] = v.z;
            AsT[kq * 4 + 3][row] = v.w;
        }
        // ---- stage B tile (32 k x 256 c) ----
#pragma unroll
        for (int p = 0; p < 8; ++p) {
            int f4 = p * 256 + tid;      // 0..2047 float4s
            int k  = f4 >> 6;            // 0..31
            int c4 = f4 & 63;            // float4 col index
            int h  = c4 >> 4;
            int j  = (c4 & 15) * 4;
            float4 v = *(const float4*)(W + (size_t)h * (IN_F * OUT_F) + (size_t)(k0 + k) * OUT_F + j);
            *(float4*)&Bs[k][c4 * 4] = v;
        }
        __syncthreads();

        for (int k = 0; k < 32; ++k) {
            float a[8], b[8];
#pragma unroll
            for (int i = 0; i < 8; ++i) a[i] = AsT[k][tr * 8 + i];
#pragma unroll
            for (int i = 0; i < 8; ++i) b[i] = Bs[k][tc * 8 + i];
#pragma unroll
            for (int i = 0; i < 8; ++i)
#pragma unroll
                for (int j = 0; j < 8; ++j) acc[i][j] += a[i] * b[j];
        }
        __syncthreads();
    }

#pragma unroll
    for (int i = 0; i < 8; ++i) {
        int r = r0 + tr * 8 + i;
        if (r < M) {
            float4 v0 = make_float4(acc[i][0], acc[i][1], acc[i][2], acc[i][3]);
            float4 v1 = make_float4(acc[i][4], acc[i][5], acc[i][6], acc[i][7]);
            *(float4*)(C + (size_t)r * NCOL + tc * 8)     = v0;
            *(float4*)(C + (size_t)r * NCOL + tc * 8 + 4) = v1;
        }
    }
}

// ---------------------------------------------------------------------------
// Kernel 2: per-node score components.
// ss1[i][h] = s_all[i, h*64:]·a1[h,:64]   ss2 with a2
// tt1[i][h] = t_all[i, h*64:]·a1[h,64:]   tt2 with a2
// One block per node; wave w handles head h=w (64 lanes = 64 j's).
// ---------------------------------------------------------------------------
__global__ __launch_bounds__(256) void dots_kernel(
    const float* __restrict__ s_all, const float* __restrict__ t_all,
    const float* __restrict__ a1, const float* __restrict__ a2,
    float* __restrict__ ss1, float* __restrict__ ss2,
    float* __restrict__ tt1, float* __restrict__ tt2)
{
    const int i = blockIdx.x;
    const int c = threadIdx.x;
    const int h = c >> 6, j = c & 63;

    float sv = s_all[(size_t)i * NCOL + c];
    float tv = t_all[(size_t)i * NCOL + c];
    float ps1 = sv * a1[h * 128 + j];
    float ps2 = sv * a2[h * 128 + j];
    float pt1 = tv * a1[h * 128 + 64 + j];
    float pt2 = tv * a2[h * 128 + 64 + j];
#pragma unroll
    for (int off = 32; off > 0; off >>= 1) {
        ps1 += __shfl_down(ps1, off, 64);
        ps2 += __shfl_down(ps2, off, 64);
        pt1 += __shfl_down(pt1, off, 64);
        pt2 += __shfl_down(pt2, off, 64);
    }
    if (j == 0) {
        ss1[i * HEADS + h] = ps1;
        ss2[i * HEADS + h] = ps2;
        tt1[i * HEADS + h] = pt1;
        tt2[i * HEADS + h] = pt2;
    }
}

__device__ __forceinline__ float lrelu(float x) {
    return x > 0.f ? x : LRELU_ALPHA * x;
}

// ---------------------------------------------------------------------------
// Kernel 3: softmax denominators. No max-subtraction (scores |e| <~ 7,
// exp bounded ~1e3; identical after normalization).
// d1[t][h] = sum_e@tgt=t exp(lrelu(ss1[src]+tt1[tgt]))
// d2[s][h] = sum_e@src=s exp(lrelu(ss2[src]+tt2[tgt]))
// ---------------------------------------------------------------------------
__global__ __launch_bounds__(256) void denom_kernel(
    const int* __restrict__ src, const int* __restrict__ tgt,
    const float* __restrict__ ss1, const float* __restrict__ ss2,
    const float* __restrict__ tt1, const float* __restrict__ tt2,
    float* __restrict__ d1, float* __restrict__ d2, int E)
{
    int e = blockIdx.x * blockDim.x + threadIdx.x;
    if (e >= E) return;
    int sn = src[e], tn = tgt[e];
    float4 s1 = *(const float4*)(ss1 + (size_t)sn * 4);
    float4 s2 = *(const float4*)(ss2 + (size_t)sn * 4);
    float4 t1 = *(const float4*)(tt1 + (size_t)tn * 4);
    float4 t2 = *(const float4*)(tt2 + (size_t)tn * 4);

    atomicAdd(&d1[tn * 4 + 0], expf(lrelu(s1.x + t1.x)));
    atomicAdd(&d1[tn * 4 + 1], expf(lrelu(s1.y + t1.y)));
    atomicAdd(&d1[tn * 4 + 2], expf(lrelu(s1.z + t1.z)));
    atomicAdd(&d1[tn * 4 + 3], expf(lrelu(s1.w + t1.w)));

    atomicAdd(&d2[sn * 4 + 0], expf(lrelu(s2.x + t2.x)));
    atomicAdd(&d2[sn * 4 + 1], expf(lrelu(s2.y + t2.y)));
    atomicAdd(&d2[sn * 4 + 2], expf(lrelu(s2.z + t2.z)));
    atomicAdd(&d2[sn * 4 + 3], expf(lrelu(s2.w + t2.w)));
}

// ---------------------------------------------------------------------------
// Kernel 4: edge aggregation (scatter with atomics). One block per edge,
// 256 threads = full 4-head feature row. Recomputes w (cheap) instead of
// storing it.
// h_ts[tgt] += (w1/d1[tgt]) * s_all[src];  h_st[src] += (w2/d2[src]) * t_all[tgt]
// ---------------------------------------------------------------------------
__global__ __launch_bounds__(256) void agg_kernel(
    const int* __restrict__ src, const int* __restrict__ tgt,
    const float* __restrict__ ss1, const float* __restrict__ ss2,
    const float* __restrict__ tt1, const float* __restrict__ tt2,
    const float* __restrict__ d1, const float* __restrict__ d2,
    const float* __restrict__ s_all, const float* __restrict__ t_all,
    float* __restrict__ h_st, float* __restrict__ h_ts)
{
    const int e = blockIdx.x;
    const int c = threadIdx.x;
    const int h = c >> 6;
    const int sn = src[e], tn = tgt[e];

    float w1 = expf(lrelu(ss1[sn * 4 + h] + tt1[tn * 4 + h]));
    float w2 = expf(lrelu(ss2[sn * 4 + h] + tt2[tn * 4 + h]));
    float coef1 = w1 / d1[tn * 4 + h];
    float coef2 = w2 / d2[sn * 4 + h];

    atomicAdd(&h_ts[(size_t)tn * NCOL + c], coef1 * s_all[(size_t)sn * NCOL + c]);
    atomicAdd(&h_st[(size_t)sn * NCOL + c], coef2 * t_all[(size_t)tn * NCOL + c]);
}

// ---------------------------------------------------------------------------
// Kernel 5: in-place ELU over the accumulated outputs.
// ---------------------------------------------------------------------------
__global__ __launch_bounds__(256) void elu_kernel(float* __restrict__ out, int n4)
{
    int i = blockIdx.x * blockDim.x + threadIdx.x;
    if (i >= n4) return;
    float4 v = ((float4*)out)[i];
    v.x = v.x > 0.f ? v.x : expm1f(v.x);
    v.y = v.y > 0.f ? v.y : expm1f(v.y);
    v.z = v.z > 0.f ? v.z : expm1f(v.z);
    v.w = v.w > 0.f ? v.w : expm1f(v.w);
    ((float4*)out)[i] = v;
}

extern "C" void kernel_launch(void* const* d_in, const int* in_sizes, int n_in,
                              void* d_out, int out_size, void* d_ws, size_t ws_size,
                              hipStream_t stream)
{
    const float* input1 = (const float*)d_in[0];
    const float* input2 = (const float*)d_in[1];
    const float* Ws     = (const float*)d_in[2];
    const float* Wt     = (const float*)d_in[3];
    const float* a1     = (const float*)d_in[4];
    const float* a2     = (const float*)d_in[5];
    const int*   tgt    = (const int*)d_in[6];   // NOTE: tgt_idx comes before src_idx
    const int*   src    = (const int*)d_in[7];

    float* out   = (float*)d_out;
    float* h_st  = out;                                   // [N, 256]
    float* h_ts  = out + (size_t)N_NODES * NCOL;          // [N, 256]

    // workspace layout (floats)
    float* ws    = (float*)d_ws;
    float* s_all = ws;                                    // 5,120,000
    float* t_all = s_all + (size_t)N_NODES * NCOL;        // 5,120,000
    float* ss1   = t_all + (size_t)N_NODES * NCOL;        // 80,000
    float* ss2   = ss1 + N_NODES * HEADS;
    float* tt1   = ss2 + N_NODES * HEADS;
    float* tt2   = tt1 + N_NODES * HEADS;
    float* d1    = tt2 + N_NODES * HEADS;
    float* d2    = d1 + N_NODES * HEADS;

    // zero accumulators (harness poisons d_out/d_ws with 0xAA)
    hipMemsetAsync(d_out, 0, (size_t)out_size * sizeof(float), stream);
    hipMemsetAsync(d1, 0, (size_t)2 * N_NODES * HEADS * sizeof(float), stream);

    dim3 ggrid((N_NODES + 63) / 64, 2);
    gemm_kernel<<<ggrid, 256, 0, stream>>>(input1, Ws, input2, Wt, s_all, t_all, N_NODES);

    dots_kernel<<<N_NODES, 256, 0, stream>>>(s_all, t_all, a1, a2, ss1, ss2, tt1, tt2);

    denom_kernel<<<(N_EDGES + 255) / 256, 256, 0, stream>>>(src, tgt, ss1, ss2, tt1, tt2, d1, d2, N_EDGES);

    agg_kernel<<<N_EDGES, 256, 0, stream>>>(src, tgt, ss1, ss2, tt1, tt2, d1, d2,
                                            s_all, t_all, h_st, h_ts);

    int n4 = out_size / 4;
    elu_kernel<<<(n4 + 255) / 256, 256, 0, stream>>>(out, n4);
}

// Round 2
// 406.150 us; speedup vs baseline: 2.1073x; 2.1073x over previous
//
#include <hip/hip_runtime.h>
#include <hip/hip_bf16.h>
#include <math.h>

#define N_NODES 20000
#define N_EDGES 320000
#define IN_F 256
#define OUT_F 64
#define HEADS 4
#define NCOL 256            // HEADS*OUT_F
#define LRELU_ALPHA 0.1f

__device__ __forceinline__ float lrelu(float x) {
    return x > 0.f ? x : LRELU_ALPHA * x;
}

// ---------------------------------------------------------------------------
// Kernel 1: C[M,256] = A[M,256] @ Weff[256,256]
// Weff[k][c] with c=h*64+j lives at W + h*IN_F*OUT_F + k*OUT_F + j
// BM=64, BN=256 (full width), BK=32. 8x8 register tile per thread.
// blockIdx.y selects (input1,Ws)->s_all vs (input2,Wt)->t_all.
// ---------------------------------------------------------------------------
__global__ __launch_bounds__(256) void gemm_kernel(
    const float* __restrict__ A0, const float* __restrict__ W0,
    const float* __restrict__ A1, const float* __restrict__ W1,
    float* __restrict__ C0, float* __restrict__ C1, int M)
{
    const float* A = (blockIdx.y == 0) ? A0 : A1;
    const float* W = (blockIdx.y == 0) ? W0 : W1;
    float* C       = (blockIdx.y == 0) ? C0 : C1;

    __shared__ float AsT[32][65];   // [k][row]; stride 65 -> conflict-free transposed stores
    __shared__ float Bs[32][NCOL];  // [k][c]

    const int tid = threadIdx.x;
    const int r0  = blockIdx.x * 64;
    const int tr  = tid >> 5;   // 0..7  -> rows tr*8..tr*8+7
    const int tc  = tid & 31;   // 0..31 -> cols tc*8..tc*8+7

    float acc[8][8];
#pragma unroll
    for (int i = 0; i < 8; ++i)
#pragma unroll
        for (int j = 0; j < 8; ++j) acc[i][j] = 0.f;

    for (int k0 = 0; k0 < IN_F; k0 += 32) {
#pragma unroll
        for (int p = 0; p < 2; ++p) {
            int f4  = p * 256 + tid;     // 0..511 float4s
            int row = f4 >> 3;           // 0..63
            int kq  = f4 & 7;
            float4 v = make_float4(0.f, 0.f, 0.f, 0.f);
            if (r0 + row < M)
                v = *(const float4*)(A + (size_t)(r0 + row) * IN_F + k0 + kq * 4);
            AsT[kq * 4 + 0][row] = v.x;
            AsT[kq * 4 + 1][row] = v.y;
            AsT[kq * 4 + 2][row] = v.z;
            AsT[kq * 4 + 3][row] = v.w;
        }
#pragma unroll
        for (int p = 0; p < 8; ++p) {
            int f4 = p * 256 + tid;      // 0..2047 float4s
            int k  = f4 >> 6;            // 0..31
            int c4 = f4 & 63;
            int h  = c4 >> 4;
            int j  = (c4 & 15) * 4;
            float4 v = *(const float4*)(W + (size_t)h * (IN_F * OUT_F) + (size_t)(k0 + k) * OUT_F + j);
            *(float4*)&Bs[k][c4 * 4] = v;
        }
        __syncthreads();

        for (int k = 0; k < 32; ++k) {
            float a[8], b[8];
#pragma unroll
            for (int i = 0; i < 8; ++i) a[i] = AsT[k][tr * 8 + i];
#pragma unroll
            for (int i = 0; i < 8; ++i) b[i] = Bs[k][tc * 8 + i];
#pragma unroll
            for (int i = 0; i < 8; ++i)
#pragma unroll
                for (int j = 0; j < 8; ++j) acc[i][j] += a[i] * b[j];
        }
        __syncthreads();
    }

#pragma unroll
    for (int i = 0; i < 8; ++i) {
        int r = r0 + tr * 8 + i;
        if (r < M) {
            float4 v0 = make_float4(acc[i][0], acc[i][1], acc[i][2], acc[i][3]);
            float4 v1 = make_float4(acc[i][4], acc[i][5], acc[i][6], acc[i][7]);
            *(float4*)(C + (size_t)r * NCOL + tc * 8)     = v0;
            *(float4*)(C + (size_t)r * NCOL + tc * 8 + 4) = v1;
        }
    }
}

// ---------------------------------------------------------------------------
// Kernel 2: per-node score components (unchanged from round 1).
// ---------------------------------------------------------------------------
__global__ __launch_bounds__(256) void dots_kernel(
    const float* __restrict__ s_all, const float* __restrict__ t_all,
    const float* __restrict__ a1, const float* __restrict__ a2,
    float* __restrict__ ss1, float* __restrict__ ss2,
    float* __restrict__ tt1, float* __restrict__ tt2)
{
    const int i = blockIdx.x;
    const int c = threadIdx.x;
    const int h = c >> 6, j = c & 63;

    float sv = s_all[(size_t)i * NCOL + c];
    float tv = t_all[(size_t)i * NCOL + c];
    float ps1 = sv * a1[h * 128 + j];
    float ps2 = sv * a2[h * 128 + j];
    float pt1 = tv * a1[h * 128 + 64 + j];
    float pt2 = tv * a2[h * 128 + 64 + j];
#pragma unroll
    for (int off = 32; off > 0; off >>= 1) {
        ps1 += __shfl_down(ps1, off, 64);
        ps2 += __shfl_down(ps2, off, 64);
        pt1 += __shfl_down(pt1, off, 64);
        pt2 += __shfl_down(pt2, off, 64);
    }
    if (j == 0) {
        ss1[i * HEADS + h] = ps1;
        ss2[i * HEADS + h] = ps2;
        tt1[i * HEADS + h] = pt1;
        tt2[i * HEADS + h] = pt2;
    }
}

// ---------------------------------------------------------------------------
// CSR build step 1: histogram of edge endpoints.
// cur_t[t] = deg_in(t), cur_s[s] = deg_out(s)  (cur arrays double as counters)
// ---------------------------------------------------------------------------
__global__ __launch_bounds__(256) void hist_kernel(
    const int* __restrict__ src, const int* __restrict__ tgt,
    int* __restrict__ cur_t, int* __restrict__ cur_s, int E)
{
    int e = blockIdx.x * blockDim.x + threadIdx.x;
    if (e >= E) return;
    atomicAdd(&cur_t[tgt[e]], 1);
    atomicAdd(&cur_s[src[e]], 1);
}

// ---------------------------------------------------------------------------
// CSR build step 2: exclusive scan of the two 20000-counters.
// grid = 2 blocks x 1024 threads; block b scans cnt array b.
// Writes off[0..N] (exclusive, off[N]=total) and resets cur[] = off[] so the
// scatter kernel can bump it.
// ---------------------------------------------------------------------------
__global__ __launch_bounds__(1024) void scan_kernel(
    int* __restrict__ cur_t, int* __restrict__ off_t,
    int* __restrict__ cur_s, int* __restrict__ off_s, int N)
{
    int* cur = blockIdx.x ? cur_s : cur_t;
    int* off = blockIdx.x ? off_s : off_t;
    __shared__ int buf[1024];
    const int tid = threadIdx.x;
    int running = 0;
    for (int base = 0; base < N; base += 1024) {
        int i = base + tid;
        int v = (i < N) ? cur[i] : 0;
        buf[tid] = v;
        __syncthreads();
#pragma unroll
        for (int d = 1; d < 1024; d <<= 1) {
            int t = (tid >= d) ? buf[tid - d] : 0;
            __syncthreads();
            buf[tid] += t;
            __syncthreads();
        }
        int incl = buf[tid];
        int total = buf[1023];
        if (i < N) {
            int excl = running + incl - v;
            off[i] = excl;
            cur[i] = excl;
        }
        running += total;
        __syncthreads();
    }
    if (tid == 0) off[N] = running;
}

// ---------------------------------------------------------------------------
// CSR build step 3: scatter the opposite endpoint into each node's segment.
// elist_t[off_t[t]..] = src ids of edges targeting t
// elist_s[off_s[s]..] = tgt ids of edges sourced at s
// (intra-segment order nondeterministic -> fp sum order only, tolerance ok)
// ---------------------------------------------------------------------------
__global__ __launch_bounds__(256) void scatter_kernel(
    const int* __restrict__ src, const int* __restrict__ tgt,
    int* __restrict__ cur_t, int* __restrict__ cur_s,
    int* __restrict__ elist_t, int* __restrict__ elist_s, int E)
{
    int e = blockIdx.x * blockDim.x + threadIdx.x;
    if (e >= E) return;
    int sn = src[e], tn = tgt[e];
    int p  = atomicAdd(&cur_t[tn], 1);
    elist_t[p] = sn;
    int p2 = atomicAdd(&cur_s[sn], 1);
    elist_s[p2] = tn;
}

// ---------------------------------------------------------------------------
// Kernel 4: CSR aggregation, no atomics. One block per (node, direction).
// dir 0 (ts): node n is the target; gather s_all[src], weights from
//             exp(lrelu(ss1[src] + tt1[n])); out -> h_ts[n].
// dir 1 (st): node n is the source; gather t_all[tgt], weights from
//             exp(lrelu(ss2[n] + tt2[tgt])); out -> h_st[n].
// Fused softmax denominator (each lane's w is wave-uniform -> den needs no
// reduction) and ELU epilogue. One coalesced non-atomic row write.
// ---------------------------------------------------------------------------
__global__ __launch_bounds__(256) void agg_kernel(
    const int* __restrict__ off_t, const int* __restrict__ elist_t,
    const int* __restrict__ off_s, const int* __restrict__ elist_s,
    const float* __restrict__ ss1, const float* __restrict__ ss2,
    const float* __restrict__ tt1, const float* __restrict__ tt2,
    const float* __restrict__ s_all, const float* __restrict__ t_all,
    float* __restrict__ h_st, float* __restrict__ h_ts)
{
    const int n   = blockIdx.x;
    const int dir = blockIdx.y;
    const int c   = threadIdx.x;
    const int h   = c >> 6;

    const int*   offp  = dir ? off_s   : off_t;
    const int*   list  = dir ? elist_s : elist_t;
    const float* table = dir ? t_all   : s_all;
    const float* nsc   = dir ? ss2     : tt1;   // node-side score component
    const float* esc   = dir ? tt2     : ss1;   // edge-side score component
    float*       outp  = dir ? h_st    : h_ts;

    const float base = nsc[n * HEADS + h];
    const int b0 = offp[n], b1 = offp[n + 1];

    float acc = 0.f, den = 0.f;
    int p = b0;
    for (; p + 1 < b1; p += 2) {
        int m0 = list[p], m1 = list[p + 1];
        float w0 = expf(lrelu(esc[m0 * HEADS + h] + base));
        float w1 = expf(lrelu(esc[m1 * HEADS + h] + base));
        float v0 = table[(size_t)m0 * NCOL + c];
        float v1 = table[(size_t)m1 * NCOL + c];
        den += w0 + w1;
        acc += w0 * v0 + w1 * v1;
    }
    if (p < b1) {
        int m0 = list[p];
        float w0 = expf(lrelu(esc[m0 * HEADS + h] + base));
        den += w0;
        acc += w0 * table[(size_t)m0 * NCOL + c];
    }

    if (den == 0.f) den = 1.f;
    float r = acc / den;
    outp[(size_t)n * NCOL + c] = (r > 0.f) ? r : expm1f(r);
}

extern "C" void kernel_launch(void* const* d_in, const int* in_sizes, int n_in,
                              void* d_out, int out_size, void* d_ws, size_t ws_size,
                              hipStream_t stream)
{
    const float* input1 = (const float*)d_in[0];
    const float* input2 = (const float*)d_in[1];
    const float* Ws     = (const float*)d_in[2];
    const float* Wt     = (const float*)d_in[3];
    const float* a1     = (const float*)d_in[4];
    const float* a2     = (const float*)d_in[5];
    const int*   tgt    = (const int*)d_in[6];   // tgt_idx precedes src_idx
    const int*   src    = (const int*)d_in[7];

    float* out  = (float*)d_out;
    float* h_st = out;                            // [N, 256]
    float* h_ts = out + (size_t)N_NODES * NCOL;   // [N, 256]

    // workspace layout
    float* ws    = (float*)d_ws;
    float* s_all = ws;                                    // 5,120,000 f
    float* t_all = s_all + (size_t)N_NODES * NCOL;        // 5,120,000 f
    float* ss1   = t_all + (size_t)N_NODES * NCOL;        // 80,000 f each
    float* ss2   = ss1 + N_NODES * HEADS;
    float* tt1   = ss2 + N_NODES * HEADS;
    float* tt2   = tt1 + N_NODES * HEADS;
    int*   off_t = (int*)(tt2 + N_NODES * HEADS);         // 20001
    int*   off_s = off_t + (N_NODES + 1);                 // 20001
    int*   cur_t = off_s + (N_NODES + 1);                 // 20000
    int*   cur_s = cur_t + N_NODES;                       // 20000
    int*   elist_t = cur_s + N_NODES;                     // 320000
    int*   elist_s = elist_t + N_EDGES;                   // 320000

    // zero only the histogram counters (harness poisons ws with 0xAA)
    hipMemsetAsync(cur_t, 0, (size_t)2 * N_NODES * sizeof(int), stream);

    dim3 ggrid((N_NODES + 63) / 64, 2);
    gemm_kernel<<<ggrid, 256, 0, stream>>>(input1, Ws, input2, Wt, s_all, t_all, N_NODES);

    hist_kernel<<<(N_EDGES + 255) / 256, 256, 0, stream>>>(src, tgt, cur_t, cur_s, N_EDGES);
    scan_kernel<<<2, 1024, 0, stream>>>(cur_t, off_t, cur_s, off_s, N_NODES);
    scatter_kernel<<<(N_EDGES + 255) / 256, 256, 0, stream>>>(src, tgt, cur_t, cur_s,
                                                              elist_t, elist_s, N_EDGES);

    dots_kernel<<<N_NODES, 256, 0, stream>>>(s_all, t_all, a1, a2, ss1, ss2, tt1, tt2);

    dim3 agrid(N_NODES, 2);
    agg_kernel<<<agrid, 256, 0, stream>>>(off_t, elist_t, off_s, elist_s,
                                          ss1, ss2, tt1, tt2, s_all, t_all, h_st, h_ts);
}

// Round 3
// 374.188 us; speedup vs baseline: 2.2873x; 1.0854x over previous
//
#include <hip/hip_runtime.h>
#include <hip/hip_bf16.h>
#include <math.h>

#define N_NODES 20000
#define N_EDGES 320000
#define IN_F 256
#define OUT_F 64
#define HEADS 4
#define NCOL 256            // HEADS*OUT_F
#define LRELU_ALPHA 0.1f

__device__ __forceinline__ float lrelu(float x) {
    return x > 0.f ? x : LRELU_ALPHA * x;
}

// ---------------------------------------------------------------------------
// Kernel 1: C[M,256] = A[M,256] @ Weff[256,256]   (f32 vector-ALU)
// Weff[k][c], c=h*64+j  ->  W + h*IN_F*OUT_F + k*OUT_F + j
// BM=64, BN=256, BK=32. 8x8 register tile per thread.
// blockIdx.y selects (input1,Ws)->s_all vs (input2,Wt)->t_all.
// ---------------------------------------------------------------------------
__global__ __launch_bounds__(256) void gemm_kernel(
    const float* __restrict__ A0, const float* __restrict__ W0,
    const float* __restrict__ A1, const float* __restrict__ W1,
    float* __restrict__ C0, float* __restrict__ C1, int M)
{
    const float* A = (blockIdx.y == 0) ? A0 : A1;
    const float* W = (blockIdx.y == 0) ? W0 : W1;
    float* C       = (blockIdx.y == 0) ? C0 : C1;

    __shared__ float AsT[32][65];   // [k][row]; +1 pad -> conflict-free
    __shared__ float Bs[32][NCOL];  // [k][c]

    const int tid = threadIdx.x;
    const int r0  = blockIdx.x * 64;
    const int tr  = tid >> 5;   // 0..7
    const int tc  = tid & 31;   // 0..31

    float acc[8][8];
#pragma unroll
    for (int i = 0; i < 8; ++i)
#pragma unroll
        for (int j = 0; j < 8; ++j) acc[i][j] = 0.f;

    for (int k0 = 0; k0 < IN_F; k0 += 32) {
#pragma unroll
        for (int p = 0; p < 2; ++p) {
            int f4  = p * 256 + tid;
            int row = f4 >> 3;
            int kq  = f4 & 7;
            float4 v = make_float4(0.f, 0.f, 0.f, 0.f);
            if (r0 + row < M)
                v = *(const float4*)(A + (size_t)(r0 + row) * IN_F + k0 + kq * 4);
            AsT[kq * 4 + 0][row] = v.x;
            AsT[kq * 4 + 1][row] = v.y;
            AsT[kq * 4 + 2][row] = v.z;
            AsT[kq * 4 + 3][row] = v.w;
        }
#pragma unroll
        for (int p = 0; p < 8; ++p) {
            int f4 = p * 256 + tid;
            int k  = f4 >> 6;
            int c4 = f4 & 63;
            int h  = c4 >> 4;
            int j  = (c4 & 15) * 4;
            float4 v = *(const float4*)(W + (size_t)h * (IN_F * OUT_F) + (size_t)(k0 + k) * OUT_F + j);
            *(float4*)&Bs[k][c4 * 4] = v;
        }
        __syncthreads();

        for (int k = 0; k < 32; ++k) {
            float a[8], b[8];
#pragma unroll
            for (int i = 0; i < 8; ++i) a[i] = AsT[k][tr * 8 + i];
#pragma unroll
            for (int i = 0; i < 8; ++i) b[i] = Bs[k][tc * 8 + i];
#pragma unroll
            for (int i = 0; i < 8; ++i)
#pragma unroll
                for (int j = 0; j < 8; ++j) acc[i][j] += a[i] * b[j];
        }
        __syncthreads();
    }

#pragma unroll
    for (int i = 0; i < 8; ++i) {
        int r = r0 + tr * 8 + i;
        if (r < M) {
            float4 v0 = make_float4(acc[i][0], acc[i][1], acc[i][2], acc[i][3]);
            float4 v1 = make_float4(acc[i][4], acc[i][5], acc[i][6], acc[i][7]);
            *(float4*)(C + (size_t)r * NCOL + tc * 8)     = v0;
            *(float4*)(C + (size_t)r * NCOL + tc * 8 + 4) = v1;
        }
    }
}

// ---------------------------------------------------------------------------
// Kernel 2: per-node score components.
// ---------------------------------------------------------------------------
__global__ __launch_bounds__(256) void dots_kernel(
    const float* __restrict__ s_all, const float* __restrict__ t_all,
    const float* __restrict__ a1, const float* __restrict__ a2,
    float* __restrict__ ss1, float* __restrict__ ss2,
    float* __restrict__ tt1, float* __restrict__ tt2)
{
    const int i = blockIdx.x;
    const int c = threadIdx.x;
    const int h = c >> 6, j = c & 63;

    float sv = s_all[(size_t)i * NCOL + c];
    float tv = t_all[(size_t)i * NCOL + c];
    float ps1 = sv * a1[h * 128 + j];
    float ps2 = sv * a2[h * 128 + j];
    float pt1 = tv * a1[h * 128 + 64 + j];
    float pt2 = tv * a2[h * 128 + 64 + j];
#pragma unroll
    for (int off = 32; off > 0; off >>= 1) {
        ps1 += __shfl_down(ps1, off, 64);
        ps2 += __shfl_down(ps2, off, 64);
        pt1 += __shfl_down(pt1, off, 64);
        pt2 += __shfl_down(pt2, off, 64);
    }
    if (j == 0) {
        ss1[i * HEADS + h] = ps1;
        ss2[i * HEADS + h] = ps2;
        tt1[i * HEADS + h] = pt1;
        tt2[i * HEADS + h] = pt2;
    }
}

// ---------------------------------------------------------------------------
// CSR build step 1: degree histogram (cur arrays double as counters).
// ---------------------------------------------------------------------------
__global__ __launch_bounds__(256) void hist_kernel(
    const int* __restrict__ src, const int* __restrict__ tgt,
    int* __restrict__ cur_t, int* __restrict__ cur_s, int E)
{
    int e = blockIdx.x * blockDim.x + threadIdx.x;
    if (e >= E) return;
    atomicAdd(&cur_t[tgt[e]], 1);
    atomicAdd(&cur_s[src[e]], 1);
}

// ---------------------------------------------------------------------------
// CSR build step 2: single-pass exclusive scan of the 20000-counters.
// grid = 2 blocks x 1024 threads; thread t serially scans its 20-element
// chunk, one Hillis-Steele block scan over the 1024 chunk sums, write back.
// ---------------------------------------------------------------------------
#define SCAN_CH 20  // ceil(20000/1024)
__global__ __launch_bounds__(1024) void scan_kernel(
    int* __restrict__ cur_t, int* __restrict__ off_t,
    int* __restrict__ cur_s, int* __restrict__ off_s, int N)
{
    int* cur = blockIdx.x ? cur_s : cur_t;
    int* off = blockIdx.x ? off_s : off_t;
    const int tid = threadIdx.x;
    const int i0  = tid * SCAN_CH;

    int local[SCAN_CH];
    int sum = 0;
#pragma unroll
    for (int j = 0; j < SCAN_CH; ++j) {
        int i = i0 + j;
        int v = (i < N) ? cur[i] : 0;
        local[j] = sum;          // exclusive within chunk
        sum += v;
    }

    __shared__ int buf[1024];
    buf[tid] = sum;
    __syncthreads();
    for (int d = 1; d < 1024; d <<= 1) {
        int t = (tid >= d) ? buf[tid - d] : 0;
        __syncthreads();
        buf[tid] += t;
        __syncthreads();
    }
    int excl  = buf[tid] - sum;   // exclusive prefix of chunk sums
    int total = buf[1023];

#pragma unroll
    for (int j = 0; j < SCAN_CH; ++j) {
        int i = i0 + j;
        if (i < N) {
            int o = excl + local[j];
            off[i] = o;
            cur[i] = o;
        }
    }
    if (tid == 0) off[N] = total;
}

// ---------------------------------------------------------------------------
// CSR build step 3: scatter opposite endpoints into segments.
// ---------------------------------------------------------------------------
__global__ __launch_bounds__(256) void scatter_kernel(
    const int* __restrict__ src, const int* __restrict__ tgt,
    int* __restrict__ cur_t, int* __restrict__ cur_s,
    int* __restrict__ elist_t, int* __restrict__ elist_s, int E)
{
    int e = blockIdx.x * blockDim.x + threadIdx.x;
    if (e >= E) return;
    int sn = src[e], tn = tgt[e];
    int p  = atomicAdd(&cur_t[tn], 1);
    elist_t[p] = sn;
    int p2 = atomicAdd(&cur_s[sn], 1);
    elist_s[p2] = tn;
}

// ---------------------------------------------------------------------------
// Kernel 4: CSR aggregation — ONE WAVE per (node, direction).
// Lane l owns cols 4l..4l+3 (all in head l>>4). Per edge the per-head weight
// is computed once (identical across the 16 lanes of a head group), the
// gathered row moves as one dwordx4 per lane. No LDS, no barriers, no
// atomics; fused softmax denominator + ELU; one coalesced 1 KB row store.
// Block = 256 threads = 4 independent nodes. grid = (5000, 2).
// ---------------------------------------------------------------------------
__global__ __launch_bounds__(256) void agg_kernel(
    const int* __restrict__ off_t, const int* __restrict__ elist_t,
    const int* __restrict__ off_s, const int* __restrict__ elist_s,
    const float* __restrict__ ss1, const float* __restrict__ ss2,
    const float* __restrict__ tt1, const float* __restrict__ tt2,
    const float* __restrict__ s_all, const float* __restrict__ t_all,
    float* __restrict__ h_st, float* __restrict__ h_ts)
{
    const int wave = threadIdx.x >> 6;
    const int lane = threadIdx.x & 63;
    const int n    = blockIdx.x * 4 + wave;   // 5000*4 == 20000 exactly
    const int dir  = blockIdx.y;
    const int h    = lane >> 4;
    const int coff = lane * 4;

    const int*   offp  = dir ? off_s   : off_t;
    const int*   list  = dir ? elist_s : elist_t;
    const float* table = dir ? t_all   : s_all;
    const float* nsc   = dir ? ss2     : tt1;   // node-side score component
    const float* esc   = dir ? tt2     : ss1;   // edge-side score component
    float*       outp  = dir ? h_st    : h_ts;

    const float base = nsc[n * HEADS + h];
    const int b0 = offp[n], b1 = offp[n + 1];

    float4 acc = make_float4(0.f, 0.f, 0.f, 0.f);
    float den = 0.f;

    int p = b0;
    for (; p + 1 < b1; p += 2) {
        int m0 = list[p], m1 = list[p + 1];
        float w0 = __expf(lrelu(esc[m0 * HEADS + h] + base));
        float w1 = __expf(lrelu(esc[m1 * HEADS + h] + base));
        float4 v0 = *(const float4*)(table + (size_t)m0 * NCOL + coff);
        float4 v1 = *(const float4*)(table + (size_t)m1 * NCOL + coff);
        den += w0 + w1;
        acc.x += w0 * v0.x + w1 * v1.x;
        acc.y += w0 * v0.y + w1 * v1.y;
        acc.z += w0 * v0.z + w1 * v1.z;
        acc.w += w0 * v0.w + w1 * v1.w;
    }
    if (p < b1) {
        int m0 = list[p];
        float w0 = __expf(lrelu(esc[m0 * HEADS + h] + base));
        float4 v0 = *(const float4*)(table + (size_t)m0 * NCOL + coff);
        den += w0;
        acc.x += w0 * v0.x;
        acc.y += w0 * v0.y;
        acc.z += w0 * v0.z;
        acc.w += w0 * v0.w;
    }

    if (den == 0.f) den = 1.f;
    float inv = 1.f / den;
    float4 r;
    r.x = acc.x * inv; r.y = acc.y * inv; r.z = acc.z * inv; r.w = acc.w * inv;
    r.x = (r.x > 0.f) ? r.x : expm1f(r.x);
    r.y = (r.y > 0.f) ? r.y : expm1f(r.y);
    r.z = (r.z > 0.f) ? r.z : expm1f(r.z);
    r.w = (r.w > 0.f) ? r.w : expm1f(r.w);
    *(float4*)(outp + (size_t)n * NCOL + coff) = r;
}

extern "C" void kernel_launch(void* const* d_in, const int* in_sizes, int n_in,
                              void* d_out, int out_size, void* d_ws, size_t ws_size,
                              hipStream_t stream)
{
    const float* input1 = (const float*)d_in[0];
    const float* input2 = (const float*)d_in[1];
    const float* Ws     = (const float*)d_in[2];
    const float* Wt     = (const float*)d_in[3];
    const float* a1     = (const float*)d_in[4];
    const float* a2     = (const float*)d_in[5];
    const int*   tgt    = (const int*)d_in[6];   // tgt_idx precedes src_idx
    const int*   src    = (const int*)d_in[7];

    float* out  = (float*)d_out;
    float* h_st = out;                            // [N, 256]
    float* h_ts = out + (size_t)N_NODES * NCOL;   // [N, 256]

    // workspace layout
    float* ws    = (float*)d_ws;
    float* s_all = ws;                                    // 5,120,000 f
    float* t_all = s_all + (size_t)N_NODES * NCOL;        // 5,120,000 f
    float* ss1   = t_all + (size_t)N_NODES * NCOL;        // 80,000 f each
    float* ss2   = ss1 + N_NODES * HEADS;
    float* tt1   = ss2 + N_NODES * HEADS;
    float* tt2   = tt1 + N_NODES * HEADS;
    int*   off_t = (int*)(tt2 + N_NODES * HEADS);         // 20001
    int*   off_s = off_t + (N_NODES + 1);                 // 20001
    int*   cur_t = off_s + (N_NODES + 1);                 // 20000
    int*   cur_s = cur_t + N_NODES;                       // 20000
    int*   elist_t = cur_s + N_NODES;                     // 320000
    int*   elist_s = elist_t + N_EDGES;                   // 320000

    // zero only the histogram counters (agg writes every output elem -> no
    // d_out memset needed)
    hipMemsetAsync(cur_t, 0, (size_t)2 * N_NODES * sizeof(int), stream);

    dim3 ggrid((N_NODES + 63) / 64, 2);
    gemm_kernel<<<ggrid, 256, 0, stream>>>(input1, Ws, input2, Wt, s_all, t_all, N_NODES);

    hist_kernel<<<(N_EDGES + 255) / 256, 256, 0, stream>>>(src, tgt, cur_t, cur_s, N_EDGES);
    scan_kernel<<<2, 1024, 0, stream>>>(cur_t, off_t, cur_s, off_s, N_NODES);
    scatter_kernel<<<(N_EDGES + 255) / 256, 256, 0, stream>>>(src, tgt, cur_t, cur_s,
                                                              elist_t, elist_s, N_EDGES);

    dots_kernel<<<N_NODES, 256, 0, stream>>>(s_all, t_all, a1, a2, ss1, ss2, tt1, tt2);

    dim3 agrid(N_NODES / 4, 2);
    agg_kernel<<<agrid, 256, 0, stream>>>(off_t, elist_t, off_s, elist_s,
                                          ss1, ss2, tt1, tt2, s_all, t_all, h_st, h_ts);
}

// Round 4
// 290.723 us; speedup vs baseline: 2.9439x; 1.2871x over previous
//
#include <hip/hip_runtime.h>
#include <math.h>

#define N_NODES 20000
#define N_EDGES 320000
#define IN_F 256
#define OUT_F 64
#define HEADS 4
#define NCOL 256            // HEADS*OUT_F
#define LRELU_ALPHA 0.1f

typedef __attribute__((ext_vector_type(8))) short short8;
typedef __attribute__((ext_vector_type(4))) float floatx4;

__device__ __forceinline__ float lrelu(float x) {
    return x > 0.f ? x : LRELU_ALPHA * x;
}
__device__ __forceinline__ unsigned short f2bf(float f) {   // RNE f32->bf16
    unsigned int u = __float_as_uint(f);
    u = (u + 0x7FFF + ((u >> 16) & 1)) >> 16;
    return (unsigned short)u;
}
__device__ __forceinline__ float bf2f(unsigned short u) {
    return __uint_as_float(((unsigned int)u) << 16);
}

// ---------------------------------------------------------------------------
// prep_w: W[h][k][j] f32  ->  Wb[c][k] bf16 with c=h*64+j (k contiguous).
// grid (16, 2): x = 16-k-row strip, y selects Ws->Wsb / Wt->Wtb.
// LDS transpose so both global read and write are wide.
// ---------------------------------------------------------------------------
__global__ __launch_bounds__(256) void prep_w_kernel(
    const float* __restrict__ Ws, const float* __restrict__ Wt,
    unsigned short* __restrict__ Wsb, unsigned short* __restrict__ Wtb)
{
    const float* W = blockIdx.y ? Wt : Ws;
    unsigned short* O = blockIdx.y ? Wtb : Wsb;
    __shared__ float tile[16][257];
    const int k0 = blockIdx.x * 16;
    const int c = threadIdx.x;
    const int h = c >> 6, j = c & 63;
#pragma unroll
    for (int r = 0; r < 16; ++r)
        tile[r][c] = W[(size_t)h * (IN_F * OUT_F) + (size_t)(k0 + r) * OUT_F + j];
    __syncthreads();
    unsigned short outv[16] __attribute__((aligned(16)));
#pragma unroll
    for (int r = 0; r < 16; ++r) outv[r] = f2bf(tile[r][c]);
    *(uint4*)(O + (size_t)c * 256 + k0)     = *(const uint4*)&outv[0];
    *(uint4*)(O + (size_t)c * 256 + k0 + 8) = *(const uint4*)&outv[8];
}

// ---------------------------------------------------------------------------
// gemm_mfma: C_bf[M,256] = A_f32[M,256] @ Wb^T (Wb is [n][k] bf16).
// BM=32 (exact: 20000 = 625*32), BN=256, BK=32. 4 waves:
//   wave = (mhalf = w&1, nhalf = w>>1); each wave: 16 rows x 8 n-tiles.
// A-fragments: direct global f32 loads (k-contig) + in-register cvt (no LDS).
// B: staged per 32-k chunk into LDS [256][40] bf16 (pad 8 -> 2-way max).
// MFMA 16x16x32_bf16; verified layouts:
//   A[m=lane&15][k=quad*8+j], B[k=quad*8+j][n=lane&15],
//   D col=lane&15, row=quad*4+reg.
// ---------------------------------------------------------------------------
__global__ __launch_bounds__(256) void gemm_mfma_kernel(
    const float* __restrict__ A0, const unsigned short* __restrict__ Wb0,
    const float* __restrict__ A1, const unsigned short* __restrict__ Wb1,
    unsigned short* __restrict__ C0, unsigned short* __restrict__ C1)
{
    const float* A            = (blockIdx.y == 0) ? A0 : A1;
    const unsigned short* Wb  = (blockIdx.y == 0) ? Wb0 : Wb1;
    unsigned short* C         = (blockIdx.y == 0) ? C0 : C1;

    __shared__ __align__(16) unsigned short Bl[256][40];   // [n][k], pad 8 bf16

    const int tid   = threadIdx.x;
    const int lane  = tid & 63;
    const int w     = tid >> 6;
    const int quad  = lane >> 4;
    const int l15   = lane & 15;
    const int mhalf = w & 1, nhalf = w >> 1;
    const int r0    = blockIdx.x * 32;
    const int mrow  = r0 + mhalf * 16 + l15;

    floatx4 acc[8];
#pragma unroll
    for (int t = 0; t < 8; ++t) acc[t] = (floatx4){0.f, 0.f, 0.f, 0.f};

    const float* arow = A + (size_t)mrow * IN_F + quad * 8;

    for (int k0 = 0; k0 < IN_F; k0 += 32) {
        // ---- stage B chunk: Wb[n][k0..k0+31], 8192 bf16, 32 per thread ----
#pragma unroll
        for (int p = 0; p < 4; ++p) {
            int idx = p * 256 + tid;
            int n = idx >> 2, kc = idx & 3;
            uint4 v = *(const uint4*)(Wb + (size_t)n * 256 + k0 + kc * 8);
            *(uint4*)&Bl[n][kc * 8] = v;
        }
        __syncthreads();

        // ---- A fragment: 8 f32 from global, cvt to bf16 ----
        float4 av0 = *(const float4*)(arow + k0);
        float4 av1 = *(const float4*)(arow + k0 + 4);
        short8 afrag;
        afrag[0] = (short)f2bf(av0.x); afrag[1] = (short)f2bf(av0.y);
        afrag[2] = (short)f2bf(av0.z); afrag[3] = (short)f2bf(av0.w);
        afrag[4] = (short)f2bf(av1.x); afrag[5] = (short)f2bf(av1.y);
        afrag[6] = (short)f2bf(av1.z); afrag[7] = (short)f2bf(av1.w);

#pragma unroll
        for (int t = 0; t < 8; ++t) {
            int n = (nhalf * 8 + t) * 16 + l15;
            short8 bfrag = *(const short8*)&Bl[n][quad * 8];
            acc[t] = __builtin_amdgcn_mfma_f32_16x16x32_bf16(afrag, bfrag, acc[t], 0, 0, 0);
        }
        __syncthreads();
    }

    // ---- epilogue: D col=lane&15, row=quad*4+reg; store bf16 ----
#pragma unroll
    for (int t = 0; t < 8; ++t) {
        int col = (nhalf * 8 + t) * 16 + l15;
#pragma unroll
        for (int r = 0; r < 4; ++r) {
            int m = r0 + mhalf * 16 + quad * 4 + r;
            C[(size_t)m * NCOL + col] = f2bf(acc[t][r]);
        }
    }
}

// ---------------------------------------------------------------------------
// dots: per-node score components from bf16 tables.
// ---------------------------------------------------------------------------
__global__ __launch_bounds__(256) void dots_kernel(
    const unsigned short* __restrict__ s_bf, const unsigned short* __restrict__ t_bf,
    const float* __restrict__ a1, const float* __restrict__ a2,
    float* __restrict__ ss1, float* __restrict__ ss2,
    float* __restrict__ tt1, float* __restrict__ tt2)
{
    const int i = blockIdx.x;
    const int c = threadIdx.x;
    const int h = c >> 6, j = c & 63;

    float sv = bf2f(s_bf[(size_t)i * NCOL + c]);
    float tv = bf2f(t_bf[(size_t)i * NCOL + c]);
    float ps1 = sv * a1[h * 128 + j];
    float ps2 = sv * a2[h * 128 + j];
    float pt1 = tv * a1[h * 128 + 64 + j];
    float pt2 = tv * a2[h * 128 + 64 + j];
#pragma unroll
    for (int off = 32; off > 0; off >>= 1) {
        ps1 += __shfl_down(ps1, off, 64);
        ps2 += __shfl_down(ps2, off, 64);
        pt1 += __shfl_down(pt1, off, 64);
        pt2 += __shfl_down(pt2, off, 64);
    }
    if (j == 0) {
        ss1[i * HEADS + h] = ps1;
        ss2[i * HEADS + h] = ps2;
        tt1[i * HEADS + h] = pt1;
        tt2[i * HEADS + h] = pt2;
    }
}

// ---------------------------------------------------------------------------
// CSR build: histogram -> single-pass scan -> scatter.
// ---------------------------------------------------------------------------
__global__ __launch_bounds__(256) void hist_kernel(
    const int* __restrict__ src, const int* __restrict__ tgt,
    int* __restrict__ cur_t, int* __restrict__ cur_s, int E)
{
    int e = blockIdx.x * blockDim.x + threadIdx.x;
    if (e >= E) return;
    atomicAdd(&cur_t[tgt[e]], 1);
    atomicAdd(&cur_s[src[e]], 1);
}

#define SCAN_CH 20  // ceil(20000/1024)
__global__ __launch_bounds__(1024) void scan_kernel(
    int* __restrict__ cur_t, int* __restrict__ off_t,
    int* __restrict__ cur_s, int* __restrict__ off_s, int N)
{
    int* cur = blockIdx.x ? cur_s : cur_t;
    int* off = blockIdx.x ? off_s : off_t;
    const int tid = threadIdx.x;
    const int i0  = tid * SCAN_CH;

    int local[SCAN_CH];
    int sum = 0;
#pragma unroll
    for (int j = 0; j < SCAN_CH; ++j) {
        int i = i0 + j;
        int v = (i < N) ? cur[i] : 0;
        local[j] = sum;
        sum += v;
    }

    __shared__ int buf[1024];
    buf[tid] = sum;
    __syncthreads();
    for (int d = 1; d < 1024; d <<= 1) {
        int t = (tid >= d) ? buf[tid - d] : 0;
        __syncthreads();
        buf[tid] += t;
        __syncthreads();
    }
    int excl  = buf[tid] - sum;
    int total = buf[1023];

#pragma unroll
    for (int j = 0; j < SCAN_CH; ++j) {
        int i = i0 + j;
        if (i < N) {
            int o = excl + local[j];
            off[i] = o;
            cur[i] = o;
        }
    }
    if (tid == 0) off[N] = total;
}

__global__ __launch_bounds__(256) void scatter_kernel(
    const int* __restrict__ src, const int* __restrict__ tgt,
    int* __restrict__ cur_t, int* __restrict__ cur_s,
    int* __restrict__ elist_t, int* __restrict__ elist_s, int E)
{
    int e = blockIdx.x * blockDim.x + threadIdx.x;
    if (e >= E) return;
    int sn = src[e], tn = tgt[e];
    int p  = atomicAdd(&cur_t[tn], 1);
    elist_t[p] = sn;
    int p2 = atomicAdd(&cur_s[sn], 1);
    elist_s[p2] = tn;
}

// ---------------------------------------------------------------------------
// agg: ONE WAVE per (node, direction), bf16 tables (8 B gathers/lane).
// Lane l owns cols 4l..4l+3 (head l>>4); per-head weight computed once per
// edge; no LDS / barriers / atomics; fused softmax denom + ELU epilogue.
// ---------------------------------------------------------------------------
__global__ __launch_bounds__(256) void agg_kernel(
    const int* __restrict__ off_t, const int* __restrict__ elist_t,
    const int* __restrict__ off_s, const int* __restrict__ elist_s,
    const float* __restrict__ ss1, const float* __restrict__ ss2,
    const float* __restrict__ tt1, const float* __restrict__ tt2,
    const unsigned short* __restrict__ s_bf, const unsigned short* __restrict__ t_bf,
    float* __restrict__ h_st, float* __restrict__ h_ts)
{
    const int wave = threadIdx.x >> 6;
    const int lane = threadIdx.x & 63;
    const int n    = blockIdx.x * 4 + wave;   // 5000*4 == 20000
    const int dir  = blockIdx.y;
    const int h    = lane >> 4;
    const int coff = lane * 4;

    const int*            offp  = dir ? off_s   : off_t;
    const int*            list  = dir ? elist_s : elist_t;
    const unsigned short* table = dir ? t_bf    : s_bf;
    const float*          nsc   = dir ? ss2     : tt1;
    const float*          esc   = dir ? tt2     : ss1;
    float*                outp  = dir ? h_st    : h_ts;

    const float base = nsc[n * HEADS + h];
    const int b0 = offp[n], b1 = offp[n + 1];

    float4 acc = make_float4(0.f, 0.f, 0.f, 0.f);
    float den = 0.f;

    int p = b0;
    for (; p + 1 < b1; p += 2) {
        int m0 = list[p], m1 = list[p + 1];
        float w0 = __expf(lrelu(esc[m0 * HEADS + h] + base));
        float w1 = __expf(lrelu(esc[m1 * HEADS + h] + base));
        ushort4 r0 = *(const ushort4*)(table + (size_t)m0 * NCOL + coff);
        ushort4 r1 = *(const ushort4*)(table + (size_t)m1 * NCOL + coff);
        den += w0 + w1;
        acc.x += w0 * bf2f(r0.x) + w1 * bf2f(r1.x);
        acc.y += w0 * bf2f(r0.y) + w1 * bf2f(r1.y);
        acc.z += w0 * bf2f(r0.z) + w1 * bf2f(r1.z);
        acc.w += w0 * bf2f(r0.w) + w1 * bf2f(r1.w);
    }
    if (p < b1) {
        int m0 = list[p];
        float w0 = __expf(lrelu(esc[m0 * HEADS + h] + base));
        ushort4 r0 = *(const ushort4*)(table + (size_t)m0 * NCOL + coff);
        den += w0;
        acc.x += w0 * bf2f(r0.x);
        acc.y += w0 * bf2f(r0.y);
        acc.z += w0 * bf2f(r0.z);
        acc.w += w0 * bf2f(r0.w);
    }

    if (den == 0.f) den = 1.f;
    float inv = 1.f / den;
    float4 r;
    r.x = acc.x * inv; r.y = acc.y * inv; r.z = acc.z * inv; r.w = acc.w * inv;
    r.x = (r.x > 0.f) ? r.x : expm1f(r.x);
    r.y = (r.y > 0.f) ? r.y : expm1f(r.y);
    r.z = (r.z > 0.f) ? r.z : expm1f(r.z);
    r.w = (r.w > 0.f) ? r.w : expm1f(r.w);
    *(float4*)(outp + (size_t)n * NCOL + coff) = r;
}

extern "C" void kernel_launch(void* const* d_in, const int* in_sizes, int n_in,
                              void* d_out, int out_size, void* d_ws, size_t ws_size,
                              hipStream_t stream)
{
    const float* input1 = (const float*)d_in[0];
    const float* input2 = (const float*)d_in[1];
    const float* Ws     = (const float*)d_in[2];
    const float* Wt     = (const float*)d_in[3];
    const float* a1     = (const float*)d_in[4];
    const float* a2     = (const float*)d_in[5];
    const int*   tgt    = (const int*)d_in[6];   // tgt_idx precedes src_idx
    const int*   src    = (const int*)d_in[7];

    float* out  = (float*)d_out;
    float* h_st = out;                            // [N, 256]
    float* h_ts = out + (size_t)N_NODES * NCOL;   // [N, 256]

    // workspace layout
    unsigned short* s_bf = (unsigned short*)d_ws;             // 5,120,000 bf16
    unsigned short* t_bf = s_bf + (size_t)N_NODES * NCOL;     // 5,120,000 bf16
    unsigned short* Wsb  = t_bf + (size_t)N_NODES * NCOL;     // 65,536 bf16
    unsigned short* Wtb  = Wsb + 256 * 256;                   // 65,536 bf16
    float* ss1  = (float*)(Wtb + 256 * 256);                  // 80,000 f each
    float* ss2  = ss1 + N_NODES * HEADS;
    float* tt1  = ss2 + N_NODES * HEADS;
    float* tt2  = tt1 + N_NODES * HEADS;
    int*   off_t = (int*)(tt2 + N_NODES * HEADS);             // 20001
    int*   off_s = off_t + (N_NODES + 1);                     // 20001
    int*   cur_t = off_s + (N_NODES + 1);                     // 20000
    int*   cur_s = cur_t + N_NODES;                           // 20000
    int*   elist_t = cur_s + N_NODES;                         // 320000
    int*   elist_s = elist_t + N_EDGES;                       // 320000

    // zero only the histogram counters
    hipMemsetAsync(cur_t, 0, (size_t)2 * N_NODES * sizeof(int), stream);

    dim3 pgrid(16, 2);
    prep_w_kernel<<<pgrid, 256, 0, stream>>>(Ws, Wt, Wsb, Wtb);

    dim3 ggrid(N_NODES / 32, 2);
    gemm_mfma_kernel<<<ggrid, 256, 0, stream>>>(input1, Wsb, input2, Wtb, s_bf, t_bf);

    hist_kernel<<<(N_EDGES + 255) / 256, 256, 0, stream>>>(src, tgt, cur_t, cur_s, N_EDGES);
    scan_kernel<<<2, 1024, 0, stream>>>(cur_t, off_t, cur_s, off_s, N_NODES);
    scatter_kernel<<<(N_EDGES + 255) / 256, 256, 0, stream>>>(src, tgt, cur_t, cur_s,
                                                              elist_t, elist_s, N_EDGES);

    dots_kernel<<<N_NODES, 256, 0, stream>>>(s_bf, t_bf, a1, a2, ss1, ss2, tt1, tt2);

    dim3 agrid(N_NODES / 4, 2);
    agg_kernel<<<agrid, 256, 0, stream>>>(off_t, elist_t, off_s, elist_s,
                                          ss1, ss2, tt1, tt2, s_bf, t_bf, h_st, h_ts);
}